// Round 1
// baseline (775.754 us; speedup 1.0000x reference)
//
#include <hip/hip_runtime.h>
#include <cstddef>

#define HD 128   // hidden dim
#define BM 64
#define BN 64
#define BK 16

__device__ __forceinline__ float reluf(float v) { return v > 0.f ? v : 0.f; }

// ---------------- transpose 128x128 (loopW -> loopW^T) ----------------
__global__ void transpose128(const float* __restrict__ in, float* __restrict__ out) {
  // grid: 128 blocks (n), 128 threads (k): out[n][k] = in[k][n]
  out[(size_t)blockIdx.x * HD + threadIdx.x] = in[(size_t)threadIdx.x * HD + blockIdx.x];
}

// ---------------- per-edge relational message + scatter-add ----------------
// msg[e,o] = sum_i x[src[e],i] * W[etype[e], i, o];  agg[dst[e], o] += msg
// One wave (64 lanes) per edge; lane handles outputs o=lane and o=lane+64.
__global__ __launch_bounds__(256) void edge_msg(
    const float* __restrict__ x, const int* __restrict__ src, const int* __restrict__ dst,
    const int* __restrict__ et, const float* __restrict__ W, float* __restrict__ agg, int E) {
  int wid = (int)(((size_t)blockIdx.x * blockDim.x + threadIdx.x) >> 6);
  if (wid >= E) return;
  int lane = threadIdx.x & 63;
  int s = src[wid], d = dst[wid], r = et[wid];
  const float* xr = x + (size_t)s * HD;
  const float* Wr = W + (size_t)r * HD * HD;
  float x0 = xr[lane], x1 = xr[lane + 64];
  float a0 = 0.f, a1 = 0.f;
#pragma unroll 16
  for (int i = 0; i < 64; ++i) {
    float xi = __shfl(x0, i, 64);
    a0 += xi * Wr[i * HD + lane];
    a1 += xi * Wr[i * HD + 64 + lane];
  }
#pragma unroll 16
  for (int i = 0; i < 64; ++i) {
    float xi = __shfl(x1, i, 64);
    a0 += xi * Wr[(64 + i) * HD + lane];
    a1 += xi * Wr[(64 + i) * HD + 64 + lane];
  }
  atomicAdd(&agg[(size_t)d * HD + lane], a0);
  atomicAdd(&agg[(size_t)d * HD + 64 + lane], a1);
}

// ---------------- generic NT GEMM: C[m,n] = epi( sum_k A[m,k]*B[n,k] ) ----------------
// B stored [N,K] row-major ("linear weight" layout). 64x64 tile, 4x4 micro, BK=16.
// EPI 0: C = acc + bias1[n]
// EPI 1: C = relu(acc + bias1[n])
// EPI 2 (DUAL): C = relu(acc1 + bias1[n] + addend[m,n]) + relu(acc2 + bias2[n]);
//               also accumulates colsum[n] += C and colsum[N+n] += C*C (for BN stats).
template<bool DUAL, int EPI>
__global__ __launch_bounds__(256) void gemm_nt(
    const float* __restrict__ A, const float* __restrict__ B1t, const float* __restrict__ B2t,
    const float* __restrict__ bias1, const float* __restrict__ bias2,
    const float* __restrict__ addend, float* __restrict__ C, float* __restrict__ colsum,
    int M, int N, int K) {
  __shared__ __align__(16) float As[BK][BM];
  __shared__ __align__(16) float B1s[BK][BN];
  __shared__ __align__(16) float B2s[BK][BN];
  __shared__ float cs[2][BN];

  int tid = threadIdx.x;
  int trow = tid >> 4;        // 0..15
  int tcol = tid & 15;        // 0..15
  int row0 = blockIdx.y * BM;
  int col0 = blockIdx.x * BN;
  int lr = tid >> 2;          // 0..63 (tile row / tile col for staging)
  int lk = (tid & 3) * 4;     // k sub-offset 0,4,8,12

  float acc1[4][4] = {};
  float acc2[4][4] = {};

  for (int k0 = 0; k0 < K; k0 += BK) {
    // stage A tile (guard rows)
    {
      int gr = row0 + lr;
      float4 v = make_float4(0.f, 0.f, 0.f, 0.f);
      if (gr < M) v = *(const float4*)&A[(size_t)gr * K + k0 + lk];
      As[lk + 0][lr] = v.x; As[lk + 1][lr] = v.y; As[lk + 2][lr] = v.z; As[lk + 3][lr] = v.w;
    }
    // stage B tiles (N always multiple of 64 here)
    {
      int gn = col0 + lr;
      float4 v = *(const float4*)&B1t[(size_t)gn * K + k0 + lk];
      B1s[lk + 0][lr] = v.x; B1s[lk + 1][lr] = v.y; B1s[lk + 2][lr] = v.z; B1s[lk + 3][lr] = v.w;
      if constexpr (DUAL) {
        float4 w = *(const float4*)&B2t[(size_t)gn * K + k0 + lk];
        B2s[lk + 0][lr] = w.x; B2s[lk + 1][lr] = w.y; B2s[lk + 2][lr] = w.z; B2s[lk + 3][lr] = w.w;
      }
    }
    __syncthreads();
#pragma unroll
    for (int kk = 0; kk < BK; ++kk) {
      float4 a4 = *(const float4*)&As[kk][trow * 4];
      float4 b4 = *(const float4*)&B1s[kk][tcol * 4];
      float a[4] = {a4.x, a4.y, a4.z, a4.w};
      float b[4] = {b4.x, b4.y, b4.z, b4.w};
#pragma unroll
      for (int i = 0; i < 4; ++i)
#pragma unroll
        for (int j = 0; j < 4; ++j) acc1[i][j] += a[i] * b[j];
      if constexpr (DUAL) {
        float4 c4 = *(const float4*)&B2s[kk][tcol * 4];
        float c[4] = {c4.x, c4.y, c4.z, c4.w};
#pragma unroll
        for (int i = 0; i < 4; ++i)
#pragma unroll
          for (int j = 0; j < 4; ++j) acc2[i][j] += a[i] * c[j];
      }
    }
    __syncthreads();
  }

  int ccol = col0 + tcol * 4;
  if constexpr (EPI == 2) {
    float s[4] = {0, 0, 0, 0}, sq[4] = {0, 0, 0, 0};
#pragma unroll
    for (int i = 0; i < 4; ++i) {
      int row = row0 + trow * 4 + i;
      if (row < M) {
#pragma unroll
        for (int j = 0; j < 4; ++j) {
          int col = ccol + j;
          float v = reluf(acc1[i][j] + bias1[col] + addend[(size_t)row * N + col])
                  + reluf(acc2[i][j] + bias2[col]);
          C[(size_t)row * N + col] = v;
          s[j] += v; sq[j] += v * v;
        }
      }
    }
    __syncthreads();
    if (tid < 2 * BN) ((float*)cs)[tid] = 0.f;
    __syncthreads();
#pragma unroll
    for (int j = 0; j < 4; ++j) {
      atomicAdd(&cs[0][tcol * 4 + j], s[j]);
      atomicAdd(&cs[1][tcol * 4 + j], sq[j]);
    }
    __syncthreads();
    if (tid < BN) {
      atomicAdd(&colsum[col0 + tid], cs[0][tid]);
      atomicAdd(&colsum[N + col0 + tid], cs[1][tid]);
    }
  } else {
#pragma unroll
    for (int i = 0; i < 4; ++i) {
      int row = row0 + trow * 4 + i;
      if (row < M) {
#pragma unroll
        for (int j = 0; j < 4; ++j) {
          int col = ccol + j;
          float v = acc1[i][j] + bias1[col];
          if constexpr (EPI == 1) v = reluf(v);
          C[(size_t)row * N + col] = v;
        }
      }
    }
  }
}

// ---------------- BatchNorm apply (training-mode batch stats) ----------------
__global__ void bn_apply(float* __restrict__ h, const float* __restrict__ colsum,
                         const float* __restrict__ gamma, const float* __restrict__ beta, int M) {
  size_t idx = (size_t)blockIdx.x * blockDim.x + threadIdx.x;
  if (idx >= (size_t)M * HD) return;
  int c = (int)(idx & (HD - 1));
  float invM = 1.f / (float)M;
  float mu = colsum[c] * invM;
  float var = colsum[HD + c] * invM - mu * mu;
  float inv = rsqrtf(var + 1e-5f);
  h[idx] = (h[idx] - mu) * inv * gamma[c] + beta[c];
}

// ---------------- segment-sum accumulation (graphs + motifs in one pass) ----------------
__global__ void seg_accum(const float* __restrict__ h, const int* __restrict__ gid,
                          const int* __restrict__ mid, float* __restrict__ gsum,
                          float* __restrict__ gcnt, float* __restrict__ msum,
                          float* __restrict__ mcnt, int Nn) {
  int node = blockIdx.x * 2 + (threadIdx.x >> 7);
  if (node >= Nn) return;
  int c = threadIdx.x & 127;
  float v = h[(size_t)node * HD + c];
  int g = gid[node], m = mid[node];
  atomicAdd(&gsum[(size_t)g * HD + c], v);
  atomicAdd(&msum[(size_t)m * HD + c], v);
  if (c == 0) { atomicAdd(&gcnt[g], 1.f); atomicAdd(&mcnt[m], 1.f); }
}

__global__ void seg_norm(const float* __restrict__ sum, const float* __restrict__ cnt,
                         float* __restrict__ out, int R) {
  size_t idx = (size_t)blockIdx.x * blockDim.x + threadIdx.x;
  if (idx >= (size_t)R * HD) return;
  int r = (int)(idx >> 7);
  out[idx] = sum[idx] / fmaxf(cnt[r], 1.f);
}

extern "C" void kernel_launch(void* const* d_in, const int* in_sizes, int n_in,
                              void* d_out, int out_size, void* d_ws, size_t ws_size,
                              hipStream_t stream) {
  const float* x0     = (const float*)d_in[0];
  const int*   src    = (const int*)d_in[1];
  const int*   dst    = (const int*)d_in[2];
  const int*   etype  = (const int*)d_in[3];
  const int*   gids   = (const int*)d_in[4];
  const int*   mids   = (const int*)d_in[5];
  const float* W1     = (const float*)d_in[6];
  const float* loopW1 = (const float*)d_in[7];
  const float* b1     = (const float*)d_in[8];
  const float* resW1  = (const float*)d_in[9];
  const float* resb1  = (const float*)d_in[10];
  const float* g1     = (const float*)d_in[11];
  const float* be1    = (const float*)d_in[12];
  const float* W2     = (const float*)d_in[13];
  const float* loopW2 = (const float*)d_in[14];
  const float* b2     = (const float*)d_in[15];
  const float* resW2  = (const float*)d_in[16];
  const float* resb2  = (const float*)d_in[17];
  const float* g2     = (const float*)d_in[18];
  const float* be2    = (const float*)d_in[19];
  const float* featW  = (const float*)d_in[20];   // [512,128]
  const float* featb  = (const float*)d_in[21];
  const float* mW1    = (const float*)d_in[22];   // [512,512]
  const float* mb1    = (const float*)d_in[23];
  const float* mW2    = (const float*)d_in[24];   // [256,512]
  const float* mb2    = (const float*)d_in[25];

  const int N = in_sizes[0] / HD;   // 30000
  const int E = in_sizes[1];        // 90000
  const int NG = 1500, NM = 6001, FFN = 512, OUT2 = 256;

  // workspace layout (f32), ~50 MB with aliasing
  float* ws = (float*)d_ws;
  size_t off = 0;
  auto alloc = [&](size_t n) { float* p = ws + off; off += (n + 63) & ~((size_t)63); return p; };
  float* agg    = alloc((size_t)N * HD);
  float* h1     = alloc((size_t)N * HD);
  float* h2     = alloc((size_t)N * HD);
  float* lwT1   = alloc(HD * HD);
  float* lwT2   = alloc(HD * HD);
  float* colsum = alloc(2 * HD);
  float* gsum   = alloc((size_t)NG * HD);
  float* gcnt   = alloc(NG);
  float* msum   = alloc((size_t)NM * HD);
  float* mcnt   = alloc(NM);
  float* fbuf = h1;   // dead after layer-2 GEMM -> reuse for head intermediate f
  float* obuf = agg;  // dead after layer-2 GEMM -> reuse for head intermediate o

  float* out_gf = (float*)d_out;                  // graph_feats [1500,128]
  float* out_gl = out_gf + (size_t)NG * HD;       // out_global  [1500,256]
  float* out_sb = out_gl + (size_t)NG * OUT2;     // out_sub     [6000,256]

  dim3 blk(256);
  int edgeBlocks = (E + 3) / 4;
  dim3 gridDual(HD / BN, (N + BM - 1) / BM);
  int bnBlocks = (int)(((size_t)N * HD + 255) / 256);

  // weight transposes for x@loopW as NT-gemm
  transpose128<<<HD, HD, 0, stream>>>(loopW1, lwT1);
  transpose128<<<HD, HD, 0, stream>>>(loopW2, lwT2);

  // ---------------- layer 1 ----------------
  hipMemsetAsync(agg, 0, (size_t)N * HD * sizeof(float), stream);
  hipMemsetAsync(colsum, 0, 2 * HD * sizeof(float), stream);
  edge_msg<<<edgeBlocks, blk, 0, stream>>>(x0, src, dst, etype, W1, agg, E);
  gemm_nt<true, 2><<<gridDual, blk, 0, stream>>>(x0, lwT1, resW1, b1, resb1, agg, h1, colsum, N, HD, HD);
  bn_apply<<<bnBlocks, blk, 0, stream>>>(h1, colsum, g1, be1, N);

  // ---------------- layer 2 ----------------
  hipMemsetAsync(agg, 0, (size_t)N * HD * sizeof(float), stream);
  hipMemsetAsync(colsum, 0, 2 * HD * sizeof(float), stream);
  edge_msg<<<edgeBlocks, blk, 0, stream>>>(h1, src, dst, etype, W2, agg, E);
  gemm_nt<true, 2><<<gridDual, blk, 0, stream>>>(h1, lwT2, resW2, b2, resb2, agg, h2, colsum, N, HD, HD);
  bn_apply<<<bnBlocks, blk, 0, stream>>>(h2, colsum, g2, be2, N);

  // ---------------- readout ----------------
  hipMemsetAsync(gsum, 0, (size_t)NG * HD * sizeof(float), stream);
  hipMemsetAsync(gcnt, 0, NG * sizeof(float), stream);
  hipMemsetAsync(msum, 0, (size_t)NM * HD * sizeof(float), stream);
  hipMemsetAsync(mcnt, 0, NM * sizeof(float), stream);
  seg_accum<<<(N + 1) / 2, blk, 0, stream>>>(h2, gids, mids, gsum, gcnt, msum, mcnt, N);
  seg_norm<<<(int)(((size_t)NG * HD + 255) / 256), blk, 0, stream>>>(gsum, gcnt, out_gf, NG);
  seg_norm<<<(int)(((size_t)NM * HD + 255) / 256), blk, 0, stream>>>(msum, mcnt, msum, NM);

  // head(g): f = g@featW^T + featb ; o = relu(f@mW1^T + mb1) ; out = o@mW2^T + mb2
  auto run_head = [&](const float* in, int M, float* outp) {
    dim3 gA(FFN / BN, (M + BM - 1) / BM);
    gemm_nt<false, 0><<<gA, blk, 0, stream>>>(in, featW, nullptr, featb, nullptr, nullptr, fbuf, nullptr, M, FFN, HD);
    dim3 gB(FFN / BN, (M + BM - 1) / BM);
    gemm_nt<false, 1><<<gB, blk, 0, stream>>>(fbuf, mW1, nullptr, mb1, nullptr, nullptr, obuf, nullptr, M, FFN, FFN);
    dim3 gC(OUT2 / BN, (M + BM - 1) / BM);
    gemm_nt<false, 0><<<gC, blk, 0, stream>>>(obuf, mW2, nullptr, mb2, nullptr, nullptr, outp, nullptr, M, OUT2, FFN);
  };
  run_head(out_gf, NG, out_gl);          // graphs: 1500 rows
  run_head(msum + HD, NM - 1, out_sb);   // motifs: rows 1..6000
}